// Round 6
// baseline (77.367 us; speedup 1.0000x reference)
//
#include <hip/hip_runtime.h>

#define DIM   4096
#define RANK  16
#define BM    16     // rows per block = MFMA M
#define NT    1024   // 16 waves -> grid 512 x 16 waves = 8192 waves = full machine
#define NWAVE 16
#define KSLICE (DIM/NWAVE)   // 256 k per wave in phase A
#define NKB   (KSLICE/32)    // 8 MFMA K-steps per wave
#define NCB   (DIM/16/NWAVE) // 16 out col-blocks per wave in phase B

typedef __fp16 f16;
typedef __fp16 half4 __attribute__((ext_vector_type(4)));
typedef __fp16 half8 __attribute__((ext_vector_type(8)));
typedef float  floatx4 __attribute__((ext_vector_type(4)));

// ---- prep: weights in exact MFMA fragment order ----
// A/B fragment mapping (16x16xK): lane&15 = row(A)/col(B), lane>>4 = k-block.
// Ub[kb][l][e] = nw[k]*U[k][l&15],          k = kb*32 + (l>>4)*8 + e   (128 KB)
// Vb[cb][l][e] = V[(l>>4)*4 + e][cb*16+l&15]                           (128 KB)
__global__ __launch_bounds__(256) void prep_weights(const float* __restrict__ U,
    const float* __restrict__ nw, const float* __restrict__ V,
    f16* __restrict__ Ub, f16* __restrict__ Vb)
{
    const int i   = blockIdx.x * 256 + threadIdx.x;   // 0..16383
    const int l   = i & 63;
    const int n   = l & 15;
    const int blk = l >> 4;
    if (i < 8192) {                     // Ub: 128 kb-steps x 64 lanes
        const int kb = i >> 6;
        half8 u;
        #pragma unroll
        for (int e = 0; e < 8; ++e) {
            const int k = kb * 32 + blk * 8 + e;
            u[e] = (f16)(nw[k] * U[(size_t)k * RANK + n]);
        }
        *(half8*)(Ub + (size_t)i * 8) = u;      // 16 B coalesced
    }
    {                                   // Vb: 256 col-blocks x 64 lanes
        const int cb = i >> 6;
        half4 v;
        #pragma unroll
        for (int e = 0; e < 4; ++e) {
            const int k = blk * 4 + e;
            v[e] = (f16)V[(size_t)k * DIM + cb * 16 + n];
        }
        *(half4*)(Vb + (size_t)i * 4) = v;      // 8 B coalesced
    }
}

// ---- fused kernel: MFMA phase A (x.U), tiny reduce, MFMA phase B (h.V) ----
// 16 waves/block, grid 512 -> exactly 2 blocks/CU = 32 waves/CU (100% occ).
// launch_bounds(1024,8) caps VGPR at 64: forces residency, leaves room for
// ~3 iterations of loads in flight (the BW*latency product needs ~3/wave).
__global__ __launch_bounds__(NT, 8) void arl_fused(
    const float* __restrict__ x,  const f16* __restrict__ Ub,
    const f16* __restrict__ Vb,   const float* __restrict__ S,
    const float* __restrict__ gamma, float* __restrict__ out)
{
    const int t   = threadIdx.x;
    const int w   = t >> 6;
    const int l   = t & 63;
    const int n   = l & 15;     // row (A-frag) / col (B,D-frags)
    const int blk = l >> 4;     // k-block / D row-group
    const size_t row0 = (size_t)blockIdx.x * BM;

    __shared__ float s_hacc[NWAVE][16][17];   // 17.4 KB, +1 pad
    __shared__ float s_ssq[NWAVE][16];
    __shared__ __align__(8) f16 s_hh[16][16];

    // ================= Phase A: acc[m][q] += x[m][k]*U'[k][q] =================
    // lane reads row (row0+n), k = w*256 + kb*32 + blk*8 + [0,8) -> 32 B/lane/iter
    const float* xlane = x + (row0 + n) * DIM + w * KSLICE + blk * 8;
    const half8* UbW   = (const half8*)Ub + (size_t)w * NKB * 64 + l;

    floatx4 acc = {0.f, 0.f, 0.f, 0.f};
    float ssq = 0.f;

    // fully unrolled: 8 independent (2x dwordx4 + 1x L2 dwordx4) load groups
    // visible to the scheduler; 64-VGPR cap keeps ~3 in flight per wave.
    #pragma unroll
    for (int kb = 0; kb < NKB; ++kb) {
        const float4 xa0 = *(const float4*)(xlane + kb * 32);
        const float4 xa1 = *(const float4*)(xlane + kb * 32 + 4);
        const half8  ub  = UbW[(size_t)kb * 64];
        ssq = fmaf(xa0.x, xa0.x, ssq); ssq = fmaf(xa0.y, xa0.y, ssq);
        ssq = fmaf(xa0.z, xa0.z, ssq); ssq = fmaf(xa0.w, xa0.w, ssq);
        ssq = fmaf(xa1.x, xa1.x, ssq); ssq = fmaf(xa1.y, xa1.y, ssq);
        ssq = fmaf(xa1.z, xa1.z, ssq); ssq = fmaf(xa1.w, xa1.w, ssq);
        half8 a;
        a[0] = (f16)xa0.x; a[1] = (f16)xa0.y; a[2] = (f16)xa0.z; a[3] = (f16)xa0.w;
        a[4] = (f16)xa1.x; a[5] = (f16)xa1.y; a[6] = (f16)xa1.z; a[7] = (f16)xa1.w;
        acc = __builtin_amdgcn_mfma_f32_16x16x32_f16(a, ub, acc, 0, 0, 0);
    }

    // ssq: sum the 4 k-block lane groups sharing a row (l, l^16, l^32, l^48)
    ssq += __shfl_xor(ssq, 16, 64);
    ssq += __shfl_xor(ssq, 32, 64);
    if (l < 16) s_ssq[w][l] = ssq;

    // spill C-fragment: D[m = blk*4+j][q = n]
    #pragma unroll
    for (int j = 0; j < 4; ++j) s_hacc[w][blk * 4 + j][n] = acc[j];
    __syncthreads();

    // ============ combine waves; fold rstd + S*keep; publish h (f16) ============
    if (t < 256) {
        const int m = t >> 4, q = t & 15;
        float hsum = 0.f, tssq = 0.f;
        #pragma unroll
        for (int ww = 0; ww < NWAVE; ++ww) {
            hsum += s_hacc[ww][m][q];
            tssq += s_ssq[ww][m];
        }
        const float rstd = rsqrtf(tssq * (1.0f / DIM) + 1e-6f);
        float tot = 0.f;
        #pragma unroll
        for (int i = 0; i < RANK; ++i) tot += fabsf(S[i]);
        const float denom = fmaxf(tot, 1e-8f);
        float cum = 0.f, se = 0.f;
        #pragma unroll
        for (int i = 0; i < RANK; ++i) {
            if (i == q) se = ((cum / denom) < 0.95f) ? S[i] : 0.f;
            cum += fabsf(S[i]);
        }
        s_hh[m][q] = (f16)(hsum * se * rstd);
    }
    __syncthreads();

    // ================= Phase B: out = x + gamma * (h . V) =================
    // A-frag (h) is loop-invariant: lane holds h[n][blk*4 .. +4)
    const half4 ah = *(const half4*)&s_hh[n][blk * 4];
    const half4* Vb4 = (const half4*)Vb;
    const floatx4 zero = {0.f, 0.f, 0.f, 0.f};

    #pragma unroll 2
    for (int i = 0; i < NCB; ++i) {
        const int cb = w * NCB + i;
        const int c0 = cb * 16;
        const half4 bv = Vb4[(size_t)cb * 64 + l];          // 8 B coalesced, L2-hot
        floatx4 d = __builtin_amdgcn_mfma_f32_16x16x16f16(ah, bv, zero, 0, 0, 0);
        const float g = gamma[c0 + n];
        const float* xr  = x   + (row0 + blk * 4) * DIM + c0 + n;   // L3-hot (phase A)
        float*       orr = out + (row0 + blk * 4) * DIM + c0 + n;
        #pragma unroll
        for (int j = 0; j < 4; ++j) {
            const float xv = xr[(size_t)j * DIM];
            __builtin_nontemporal_store(fmaf(g, d[j], xv), orr + (size_t)j * DIM);
        }
    }
}

extern "C" void kernel_launch(void* const* d_in, const int* in_sizes, int n_in,
                              void* d_out, int out_size, void* d_ws, size_t ws_size,
                              hipStream_t stream) {
    (void)in_sizes; (void)n_in; (void)ws_size;
    const float* x  = (const float*)d_in[0];
    const float* U  = (const float*)d_in[1];
    const float* S  = (const float*)d_in[2];
    const float* V  = (const float*)d_in[3];
    const float* nw = (const float*)d_in[4];
    const float* g  = (const float*)d_in[5];
    float* out = (float*)d_out;
    f16* Ub = (f16*)d_ws;                          // 128 KB fragment-order U'
    f16* Vb = (f16*)((char*)d_ws + 128 * 1024);    // 128 KB fragment-order V

    hipLaunchKernelGGL(prep_weights, dim3(64), dim3(256), 0, stream,
                       U, nw, V, Ub, Vb);

    const int rows = out_size / DIM;               // 8192
    const int grid = rows / BM;                    // 512
    hipLaunchKernelGGL(arl_fused, dim3(grid), dim3(NT), 0, stream,
                       x, Ub, Vb, S, g, out);
}

// Round 7
// 74.315 us; speedup vs baseline: 1.0411x; 1.0411x over previous
//
#include <hip/hip_runtime.h>

#define DIM   4096
#define RANK  16
#define BM    16     // rows per block = MFMA M
#define NT    512    // 8 waves
#define NWAVE 8
#define KSLICE (DIM/NWAVE)   // 512 k per wave in phase A
#define NKB   (KSLICE/32)    // 16 MFMA K-steps per wave
#define NCB   (DIM/16/NWAVE) // 32 out col-blocks per wave in phase B

typedef __fp16 f16;
typedef __fp16 half4 __attribute__((ext_vector_type(4)));
typedef __fp16 half8 __attribute__((ext_vector_type(8)));
typedef float  floatx4 __attribute__((ext_vector_type(4)));

// counted vmcnt wait + scheduling fence (rule #18: pin the following ds_reads)
#define VM_WAIT(N) { asm volatile("s_waitcnt vmcnt(" #N ")" ::: "memory"); \
                     __builtin_amdgcn_sched_barrier(0); }

// async global->LDS DMA, 16 B per lane; dest = uniform base + lane*16 (HW rule)
__device__ __forceinline__ void gld16(const void* g, void* l) {
    __builtin_amdgcn_global_load_lds((__attribute__((address_space(1))) void*)g,
                                     (__attribute__((address_space(3))) void*)l,
                                     16, 0, 0);
}

// ---- prep: weights in exact MFMA fragment order ----
// A/B fragment mapping (16x16xK): lane&15 = row(A)/col(B), lane>>4 = k-block.
// Ub[kb][l][e] = nw[k]*U[k][l&15],          k = kb*32 + (l>>4)*8 + e   (128 KB)
// Vb[cb][l][e] = V[(l>>4)*4 + e][cb*16+l&15]                           (128 KB)
__global__ __launch_bounds__(256) void prep_weights(const float* __restrict__ U,
    const float* __restrict__ nw, const float* __restrict__ V,
    f16* __restrict__ Ub, f16* __restrict__ Vb)
{
    const int i   = blockIdx.x * 256 + threadIdx.x;   // 0..16383
    const int l   = i & 63;
    const int n   = l & 15;
    const int blk = l >> 4;
    if (i < 8192) {                     // Ub: 128 kb-steps x 64 lanes
        const int kb = i >> 6;
        half8 u;
        #pragma unroll
        for (int e = 0; e < 8; ++e) {
            const int k = kb * 32 + blk * 8 + e;
            u[e] = (f16)(nw[k] * U[(size_t)k * RANK + n]);
        }
        *(half8*)(Ub + (size_t)i * 8) = u;      // 16 B coalesced
    }
    {                                   // Vb: 256 col-blocks x 64 lanes
        const int cb = i >> 6;
        half4 v;
        #pragma unroll
        for (int e = 0; e < 4; ++e) {
            const int k = blk * 4 + e;
            v[e] = (f16)V[(size_t)k * DIM + cb * 16 + n];
        }
        *(half4*)(Vb + (size_t)i * 4) = v;      // 8 B coalesced
    }
}

// ---- fused kernel ----
// Phase A: per-wave 2-deep global_load_lds ring (x frag-gather + Ub), counted
// vmcnt(3) -> loads always in flight, zero VGPR pressure from staging.
// Phase B: operand-swapped MFMA gives lane 4 consecutive cols of one row ->
// float4 residual/store.
__global__ __launch_bounds__(NT, 4) void arl_fused(
    const float* __restrict__ x,  const f16* __restrict__ Ub,
    const f16* __restrict__ Vb,   const float* __restrict__ S,
    const float* __restrict__ gamma, float* __restrict__ out)
{
    const int t   = threadIdx.x;
    const int w   = t >> 6;
    const int l   = t & 63;
    const int n   = l & 15;     // A-frag row / B,D-frag col
    const int blk = l >> 4;     // k-block / D row-group
    const size_t row0 = (size_t)blockIdx.x * BM;

    // ring slot layout (floats): [0,256) xa0 | [256,512) xa1 | [512,768) ub(f16)
    __shared__ __align__(16) float ring[NWAVE][2][768];   // 48 KB
    __shared__ float s_hacc[NWAVE][16][17];               // 8.5 KB (+1 pad)
    __shared__ float s_ssq[NWAVE][16];
    __shared__ __align__(8) f16 s_hh[16][16];

    // per-lane global sources (scatter is fine: DMA source is per-lane)
    const float* xsrc  = x + (row0 + n) * DIM + w * KSLICE + blk * 8;
    const f16*   ubsrc = Ub + ((size_t)(w * NKB) * 64 + l) * 8;

    // ================= Phase A: acc[m][q] += x[m][k]*U'[k][q] =================
    floatx4 acc = {0.f, 0.f, 0.f, 0.f};
    float ssq = 0.f;

    // prologue: slot 0 in flight (3 DMA insts)
    {
        float* slot = &ring[w][0][0];
        gld16(xsrc,             slot);
        gld16(xsrc + 4,         slot + 256);
        gld16(ubsrc,            slot + 512);
    }

    #pragma unroll
    for (int kb = 0; kb < NKB; ++kb) {
        __builtin_amdgcn_sched_barrier(0);      // keep issue inside this iter
        if (kb + 1 < NKB) {                     // issue next slot -> 6 outstanding
            float* slot = &ring[w][(kb + 1) & 1][0];
            gld16(xsrc + (kb + 1) * 32,      slot);
            gld16(xsrc + (kb + 1) * 32 + 4,  slot + 256);
            gld16(ubsrc + (size_t)(kb + 1) * 512, slot + 512);
        }
        if (kb < NKB - 1) VM_WAIT(3) else VM_WAIT(0)    // slot kb landed

        const int s = kb & 1;
        const float4 xa0 = *(const float4*)&ring[w][s][l * 4];
        const float4 xa1 = *(const float4*)&ring[w][s][256 + l * 4];
        const half8  ub  = *(const half8*)((const f16*)&ring[w][s][512] + l * 8);

        ssq = fmaf(xa0.x, xa0.x, ssq); ssq = fmaf(xa0.y, xa0.y, ssq);
        ssq = fmaf(xa0.z, xa0.z, ssq); ssq = fmaf(xa0.w, xa0.w, ssq);
        ssq = fmaf(xa1.x, xa1.x, ssq); ssq = fmaf(xa1.y, xa1.y, ssq);
        ssq = fmaf(xa1.z, xa1.z, ssq); ssq = fmaf(xa1.w, xa1.w, ssq);
        half8 a;
        a[0] = (f16)xa0.x; a[1] = (f16)xa0.y; a[2] = (f16)xa0.z; a[3] = (f16)xa0.w;
        a[4] = (f16)xa1.x; a[5] = (f16)xa1.y; a[6] = (f16)xa1.z; a[7] = (f16)xa1.w;
        acc = __builtin_amdgcn_mfma_f32_16x16x32_f16(a, ub, acc, 0, 0, 0);
    }

    // ssq: sum the 4 k-block lane groups sharing a row (l, l^16, l^32, l^48)
    ssq += __shfl_xor(ssq, 16, 64);
    ssq += __shfl_xor(ssq, 32, 64);
    if (l < 16) s_ssq[w][l] = ssq;

    // spill C-fragment: D[m = blk*4+j][q = n]
    #pragma unroll
    for (int j = 0; j < 4; ++j) s_hacc[w][blk * 4 + j][n] = acc[j];
    __syncthreads();

    // ============ combine waves; fold rstd + S*keep; publish h (f16) ============
    if (t < 256) {
        const int m = t >> 4, q = t & 15;
        float hsum = 0.f, tssq = 0.f;
        #pragma unroll
        for (int ww = 0; ww < NWAVE; ++ww) {
            hsum += s_hacc[ww][m][q];
            tssq += s_ssq[ww][m];
        }
        const float rstd = rsqrtf(tssq * (1.0f / DIM) + 1e-6f);
        float tot = 0.f;
        #pragma unroll
        for (int i = 0; i < RANK; ++i) tot += fabsf(S[i]);
        const float denom = fmaxf(tot, 1e-8f);
        float cum = 0.f, se = 0.f;
        #pragma unroll
        for (int i = 0; i < RANK; ++i) {
            if (i == q) se = ((cum / denom) < 0.95f) ? S[i] : 0.f;
            cum += fabsf(S[i]);
        }
        s_hh[m][q] = (f16)(hsum * se * rstd);
    }
    __syncthreads();

    // ================= Phase B: out = x + gamma * (h . V) =================
    // Operand swap: D' = mfma(bv, ah) = (h.V)^T per tile. D'-layout: col(lane&15)
    // = out-ROW n, row(blk*4+j) = out-col offset -> lane owns out[row0+n][c0..c0+4)
    // as a float4: single float4 residual load + store per iter.
    const half4 ah = *(const half4*)&s_hh[n][blk * 4];    // h[n][blk*4..+4)
    const half4* Vb4 = (const half4*)Vb;
    const floatx4 zero = {0.f, 0.f, 0.f, 0.f};
    const float* xrow = x   + (row0 + n) * DIM;
    float*       orow = out + (row0 + n) * DIM;

    #pragma unroll 4
    for (int i = 0; i < NCB; ++i) {
        const int cb = w * NCB + i;
        const int c0 = cb * 16 + blk * 4;
        const half4 bv = Vb4[(size_t)cb * 64 + l];          // 8 B coalesced, L2-hot
        floatx4 d = __builtin_amdgcn_mfma_f32_16x16x16f16(bv, ah, zero, 0, 0, 0);
        const float4 g  = *(const float4*)(gamma + c0);     // broadcast per blk
        const float4 xv = *(const float4*)(xrow + c0);      // L3-hot residual
        floatx4 o;
        o[0] = fmaf(g.x, d[0], xv.x);
        o[1] = fmaf(g.y, d[1], xv.y);
        o[2] = fmaf(g.z, d[2], xv.z);
        o[3] = fmaf(g.w, d[3], xv.w);
        __builtin_nontemporal_store(o, (floatx4*)(orow + c0));
    }
}

extern "C" void kernel_launch(void* const* d_in, const int* in_sizes, int n_in,
                              void* d_out, int out_size, void* d_ws, size_t ws_size,
                              hipStream_t stream) {
    (void)in_sizes; (void)n_in; (void)ws_size;
    const float* x  = (const float*)d_in[0];
    const float* U  = (const float*)d_in[1];
    const float* S  = (const float*)d_in[2];
    const float* V  = (const float*)d_in[3];
    const float* nw = (const float*)d_in[4];
    const float* g  = (const float*)d_in[5];
    float* out = (float*)d_out;
    f16* Ub = (f16*)d_ws;                          // 128 KB fragment-order U'
    f16* Vb = (f16*)((char*)d_ws + 128 * 1024);    // 128 KB fragment-order V

    hipLaunchKernelGGL(prep_weights, dim3(64), dim3(256), 0, stream,
                       U, nw, V, Ub, Vb);

    const int rows = out_size / DIM;               // 8192
    const int grid = rows / BM;                    // 512
    hipLaunchKernelGGL(arl_fused, dim3(grid), dim3(NT), 0, stream,
                       x, Ub, Vb, S, g, out);
}